// Round 9
// baseline (729.699 us; speedup 1.0000x reference)
//
#include <hip/hip_runtime.h>

#define SEQ 64
#define BAT 256
#define NT 32
#define EMB 256
#define HID 256
#define G3 768   // 3*HID

typedef __bf16 bf16x8 __attribute__((ext_vector_type(8)));
typedef __bf16 bf16x4 __attribute__((ext_vector_type(4)));
typedef float f32x4 __attribute__((ext_vector_type(4)));

__device__ __forceinline__ float sigm_fast(float x) {
    return __builtin_amdgcn_rcpf(1.f + __expf(-x));   // inf-safe
}
__device__ __forceinline__ float tanh_fast(float x) {
    return 1.f - 2.f * __builtin_amdgcn_rcpf(__expf(2.f * x) + 1.f);
}
__device__ __forceinline__ float sigm(float x) {
    x = fminf(fmaxf(x, -30.f), 30.f);
    return 1.f / (1.f + __expf(-x));
}
__device__ __forceinline__ float tanhr(float x) {
    x = fminf(fmaxf(x, -15.f), 15.f);
    float e = __expf(2.f * x);
    return (e - 1.f) / (e + 1.f);
}

// ---- K1: G = emb @ W_ih.T + b_ih ; W_hh -> fp8 frag-pack ; W_lin -> bf16 frag-pack ----
__global__ void k_pre(const float* __restrict__ emb, const float* __restrict__ W_ih,
                      const float* __restrict__ b_ih, const float* __restrict__ W_hh,
                      const float* __restrict__ W_lin,
                      float* __restrict__ G, int2* __restrict__ Wpk8, __bf16* __restrict__ Wlpk)
{
    const int tid = threadIdx.x;
    const int blk = blockIdx.x;
    if (blk < 33) {
        __shared__ float es[EMB];
        es[tid] = emb[blk * EMB + tid];
        __syncthreads();
        const float4* e4 = (const float4*)es;
        #pragma unroll
        for (int g = 0; g < 3; ++g) {
            int c = g * HID + tid;
            const float4* w4 = (const float4*)(W_ih + c * EMB);
            float acc = b_ih[c];
            #pragma unroll 8
            for (int i = 0; i < EMB / 4; ++i) {
                float4 a = e4[i], w = w4[i];
                acc += a.x * w.x + a.y * w.y + a.z * w.z + a.w * w.w;
            }
            G[blk * G3 + c] = acc;
        }
    } else if (blk < 129) {                 // W_hh fp8 pack: 24576 chunks
        int idx  = (blk - 33) * 256 + tid;
        int c    = idx >> 9;
        int rem  = idx & 511;
        int kt   = rem >> 6;
        int lane = rem & 63;
        int row  = c * 16 + (lane & 15);
        int col  = kt * 32 + (lane >> 4) * 8;
        const float* src = W_hh + row * 256 + col;
        int lo = __builtin_amdgcn_cvt_pk_fp8_f32(src[0], src[1], 0, 0);
        lo     = __builtin_amdgcn_cvt_pk_fp8_f32(src[2], src[3], lo, 1);
        int hi = __builtin_amdgcn_cvt_pk_fp8_f32(src[4], src[5], 0, 0);
        hi     = __builtin_amdgcn_cvt_pk_fp8_f32(src[6], src[7], hi, 1);
        Wpk8[idx] = make_int2(lo, hi);
    } else {                                // W_lin bf16 pack: 1024 chunks
        int i2   = (blk - 129) * 256 + tid;
        int nt   = i2 >> 9;
        int rem  = i2 & 511;
        int kt   = rem >> 6;
        int lane = rem & 63;
        int row  = nt * 16 + (lane & 15);
        int col  = kt * 32 + (lane >> 4) * 8;
        const float* src = W_lin + row * 256 + col;
        bf16x8 v;
        #pragma unroll
        for (int j = 0; j < 8; ++j) v[j] = (__bf16)src[j];
        *(bf16x8*)(Wlpk + i2 * 8) = v;
    }
}

// ---- K2: h1 = gru(emb[32], 0), trans0 = h1 @ W_lin.T + b_lin (exact fp32) ----
__global__ void k_init(const float* __restrict__ G, const float* __restrict__ b_hh,
                       const float* __restrict__ W_lin, const float* __restrict__ b_lin,
                       float* __restrict__ h1, float* __restrict__ tr0)
{
    __shared__ float hs[HID];
    int j = threadIdx.x;
    float gr = G[32 * G3 + j], gz = G[32 * G3 + HID + j], gn = G[32 * G3 + 2 * HID + j];
    float r = sigm(gr + b_hh[j]);
    float z = sigm(gz + b_hh[HID + j]);
    float n = tanhr(gn + r * b_hh[2 * HID + j]);
    float h = (1.f - z) * n;   // h0 = 0
    h1[j] = h; hs[j] = h;
    __syncthreads();
    if (j < NT) {
        const float4* w4 = (const float4*)(W_lin + j * HID);
        const float4* h4 = (const float4*)hs;
        float acc = b_lin[j];
        #pragma unroll 8
        for (int i = 0; i < HID / 4; ++i) {
            float4 a = h4[i], w = w4[i];
            acc += a.x * w.x + a.y * w.y + a.z * w.z + a.w * w.w;
        }
        tr0[j] = acc;
    }
}

// merge-step helper: comparator (v desc, idx asc); 5-stage bitonic clean within 32-lane half
#define CMP_MAX(av, ai, bv, bi, mv, mi)                          \
    if ((av) > (bv) || ((av) == (bv) && (ai) < (bi))) { mv = (av); mi = (ai); } \
    else                                               { mv = (bv); mi = (bi); }
#define CLEAN32(mv, mi, l32)                                      \
    _Pragma("unroll")                                             \
    for (int off = 16; off >= 1; off >>= 1) {                     \
        float ov = __shfl_xor(mv, off, 64);                       \
        int   oi = __shfl_xor(mi, off, 64);                       \
        bool up = ((l32) & off) == 0;                             \
        bool omax = (ov > mv) || (ov == mv && oi < mi);           \
        if (up == omax) { mv = ov; mi = oi; }                     \
    }

union ZCast { int4 i; bf16x8 v; };

// ---- K3: one 1024-thread workgroup per batch element; fp8 W_hh register-stationary;
//          gl4 gate-interleaved (1 b64/row in GRU), no zero-pad rows (broadcast+cndmask).
__global__ __launch_bounds__(1024, 1) void k_main(
    const float* __restrict__ em, const int* __restrict__ tags, const float* __restrict__ mask,
    const float* __restrict__ G, const float* __restrict__ h1w, const float* __restrict__ tr0w,
    const long* __restrict__ Wpk8, const __bf16* __restrict__ Wlpk,
    const float* __restrict__ bhhg, const float* __restrict__ bling,
    float* __restrict__ out)
{
    __shared__ __attribute__((aligned(16))) __bf16 gl4[32 * 256 * 4]; // [e][j][{r,z,n,pad}] 64 KB
    __shared__ __attribute__((aligned(16))) __bf16 hb[2][33 * 264];   // bf16 state ping-pong (33 rows)
    __shared__ __attribute__((aligned(16))) unsigned char hq[33 * 264]; // fp8 permuted A (33 rows)
    __shared__ __attribute__((aligned(16))) __bf16 wlin[8192];        // packed W_lin frags (bf16)
    __shared__ float trs[33 * 33];
    __shared__ float srtv[16 * 33];
    __shared__ unsigned short srti[16 * 33];
    __shared__ float em_s[SEQ * NT];
    __shared__ float mask_s[SEQ];
    __shared__ int tags_s[SEQ];
    __shared__ float scores[NT];
    __shared__ int btag[NT], par[NT];
    __shared__ float s_ps;

    const int tid = threadIdx.x;
    const int b = blockIdx.x;
    const int w = tid >> 6;
    const int lane = tid & 63;
    const int q = lane >> 4;
    const int l15 = lane & 15;
    const int j = w * 16 + l15;          // this lane's hidden column

    // ---- register-stationary W_hh fragments & biases ----
    long wreg[24];
    #pragma unroll
    for (int g = 0; g < 3; ++g)
        #pragma unroll
        for (int kt = 0; kt < 8; ++kt)
            wreg[g * 8 + kt] = Wpk8[((g * 16 + w) * 8 + kt) * 64 + lane];
    const float br_ = bhhg[j], bz_ = bhhg[256 + j], bn_ = bhhg[512 + j];
    float bl_ = 0.f;
    if (w < 6) bl_ = bling[(w & 1) * 16 + l15];

    // ---- prologue staging ----
    if (tid < 64) mask_s[tid] = mask[tid * BAT + b];
    else if (tid < 128) tags_s[tid - 64] = tags[(tid - 64) * BAT + b];
    else if (tid < 160) par[tid - 128] = tid - 128;
    ((bf16x8*)wlin)[tid] = ((const bf16x8*)Wlpk)[tid];
    for (int idx = tid; idx < SEQ * NT; idx += 1024)
        em_s[idx] = em[((idx >> 5) * BAT + b) * NT + (idx & 31)];
    for (int idx = tid; idx < 32 * 256; idx += 1024) {      // gl4: embeddings 0..31 only
        int e = idx >> 8, jj = idx & 255;
        const float* gp = G + e * G3 + jj;
        bf16x4 g4;
        g4[0] = (__bf16)gp[0]; g4[1] = (__bf16)gp[256]; g4[2] = (__bf16)gp[512];
        g4[3] = (__bf16)0.f;
        *(bf16x4*)&gl4[idx * 4] = g4;
    }
    for (int idx = tid; idx < 33 * 256; idx += 1024)
        hb[0][(idx >> 8) * 264 + (idx & 255)] = (__bf16)h1w[idx & 255];
    __syncthreads();

    // ---- initial top_k of s_init = (trans0 + em0) * mask0 (rank sort, ties -> lower idx) ----
    if (tid < 32) {
        float m0 = mask_s[0];
        float v = (tr0w[tid] + em_s[tid]) * m0;
        int cnt = 0;
        for (int jj = 0; jj < 32; ++jj) {
            float vj = __shfl(v, jj, 32);
            cnt += (vj > v) || (vj == v && jj < tid);
        }
        scores[cnt] = v; btag[cnt] = tid;
    }
    if (tid == 64) {
        int t0 = tags_s[0];
        s_ps = (tr0w[t0] + em_s[t0]) * mask_s[0];
    }
    __syncthreads();

    for (int t = 1; t < SEQ; ++t) {
        const int cur = (t - 1) & 1, nxt = t & 1;

        // (b) hq <- fp8(parent-permuted h) ; permutation applied at WRITE
        for (int c = tid; c < 33 * 32; c += 1024) {
            int row = c >> 5, off = (c & 31) * 8;
            int src = (row < 32) ? par[row] : 32;
            bf16x8 hv = *(const bf16x8*)&hb[cur][src * 264 + off];
            int lo = __builtin_amdgcn_cvt_pk_fp8_f32((float)hv[0], (float)hv[1], 0, 0);
            lo     = __builtin_amdgcn_cvt_pk_fp8_f32((float)hv[2], (float)hv[3], lo, 1);
            int hi = __builtin_amdgcn_cvt_pk_fp8_f32((float)hv[4], (float)hv[5], 0, 0);
            hi     = __builtin_amdgcn_cvt_pk_fp8_f32((float)hv[6], (float)hv[7], hi, 1);
            *(int2*)&hq[row * 264 + off] = make_int2(lo, hi);
        }
        __syncthreads();

        // (c) gh = hidden @ W_hh.T (fp8; af2 row 32 via broadcast + lane-mask zero)
        f32x4 acc[3][3];
        #pragma unroll
        for (int mt = 0; mt < 3; ++mt)
            #pragma unroll
            for (int g = 0; g < 3; ++g) {
                f32x4 z = {0.f, 0.f, 0.f, 0.f};
                acc[mt][g] = z;
            }
        #pragma unroll
        for (int kt = 0; kt < 8; ++kt) {
            const int kb = kt * 32 + q * 8;
            long af0 = *(const long*)&hq[l15 * 264 + kb];
            long af1 = *(const long*)&hq[(16 + l15) * 264 + kb];
            long t2  = *(const long*)&hq[32 * 264 + kb];        // broadcast read
            long af2 = (l15 == 0) ? t2 : 0L;                    // rows 33..47 are zero
            #pragma unroll
            for (int g = 0; g < 3; ++g) {
                acc[0][g] = __builtin_amdgcn_mfma_f32_16x16x32_fp8_fp8(af0, wreg[g * 8 + kt], acc[0][g], 0, 0, 0);
                acc[1][g] = __builtin_amdgcn_mfma_f32_16x16x32_fp8_fp8(af1, wreg[g * 8 + kt], acc[1][g], 0, 0, 0);
                acc[2][g] = __builtin_amdgcn_mfma_f32_16x16x32_fp8_fp8(af2, wreg[g * 8 + kt], acc[2][g], 0, 0, 0);
            }
        }

        // (d1) GRU elementwise; gi via single b64 from gate-interleaved gl4
        {
            const int pt = tags_s[t - 1];
            #pragma unroll
            for (int mt = 0; mt < 2; ++mt) {
                #pragma unroll
                for (int r = 0; r < 4; ++r) {
                    const int row = mt * 16 + q * 4 + r;          // 0..31
                    const int e = btag[row], src = par[row];
                    bf16x4 g4 = *(const bf16x4*)&gl4[(e * 256 + j) * 4];
                    float rr = sigm_fast((float)g4[0] + acc[mt][0][r] + br_);
                    float zz = sigm_fast((float)g4[1] + acc[mt][1][r] + bz_);
                    float nn = tanh_fast((float)g4[2] + rr * (acc[mt][2][r] + bn_));
                    float hold = (float)hb[cur][src * 264 + j];
                    hb[nxt][row * 264 + j] = (__bf16)(zz * (hold - nn) + nn);
                }
            }
            if (lane < 16) {                                      // path row 32 (mt=2,q=0,r=0)
                bf16x4 g4 = *(const bf16x4*)&gl4[(pt * 256 + j) * 4];
                float rr = sigm_fast((float)g4[0] + acc[2][0][0] + br_);
                float zz = sigm_fast((float)g4[1] + acc[2][1][0] + bz_);
                float nn = tanh_fast((float)g4[2] + rr * (acc[2][2][0] + bn_));
                float hold = (float)hb[cur][32 * 264 + j];
                hb[nxt][32 * 264 + j] = (__bf16)(zz * (hold - nn) + nn);
            }
        }
        __syncthreads();

        // (e) tr = hnew @ W_lin.T + b_lin (bf16; waves 0..5: mt = w>>1, coltile = w&1;
        //     mt=2 A-rows 33..47 are zero -> broadcast row 32 + lane-mask)
        if (w < 6) {
            const int mt = w >> 1, ntc = w & 1;
            f32x4 a2 = {0.f, 0.f, 0.f, 0.f};
            #pragma unroll
            for (int kt = 0; kt < 8; ++kt) {
                const int kk = kt * 32 + q * 8;
                bf16x8 af;
                if (mt < 2) {
                    af = *(const bf16x8*)&hb[nxt][(mt * 16 + l15) * 264 + kk];
                } else {
                    bf16x8 tv = *(const bf16x8*)&hb[nxt][32 * 264 + kk];  // broadcast
                    ZCast zz; zz.i = make_int4(0, 0, 0, 0);
                    af = (l15 == 0) ? tv : zz.v;
                }
                bf16x8 bv = *(const bf16x8*)&wlin[((ntc * 8 + kt) * 64 + lane) * 8];
                a2 = __builtin_amdgcn_mfma_f32_16x16x32_bf16(af, bv, a2, 0, 0, 0);
            }
            #pragma unroll
            for (int r = 0; r < 4; ++r) {
                int row = mt * 16 + q * 4 + r;
                if (row <= 32) trs[row * 33 + ntc * 16 + l15] = a2[r] + bl_;
            }
        }
        __syncthreads();

        // (f) path score + rank-sort via ds_permute + intra-wave merge L1 -> srtv row w
        const float m_t = mask_s[t];
        if (tid == 0) {
            int ct = tags_s[t];
            s_ps += (trs[32 * 33 + ct] + em_s[ct]) * m_t;
        }
        {
            const int half = lane >> 5, l32 = lane & 31;
            const int k = w * 2 + half;                 // this half's candidate row
            float bse = scores[btag[k]];                // faithful quirk: gather by prev TAG id
            float v = bse + (trs[k * 33 + l32] + em_s[t * 32 + l32]) * m_t;
            int fidx = k * 32 + l32;
            int cnt = 0;
            #pragma unroll
            for (int jj = 0; jj < 32; ++jj) {
                float vj = __shfl(v, jj, 32);
                cnt += (vj > v) || (vj == v && jj < l32);
            }
            // in-register scatter: sorted position within this half's 32 lanes
            int tgt = (half * 32 + cnt) * 4;
            float sv = __int_as_float(__builtin_amdgcn_ds_permute(tgt, __float_as_int(v)));
            int   si = __builtin_amdgcn_ds_permute(tgt, fidx);
            // cross-half merge (rows 2w, 2w+1): partner at reversed index = lane^63
            float pv = __shfl_xor(sv, 63, 64);
            int   pi = __shfl_xor(si, 63, 64);
            float mv; int mi;
            CMP_MAX(sv, si, pv, pi, mv, mi);
            CLEAN32(mv, mi, l32);
            if (half == 0) {
                srtv[w * 33 + l32] = mv;
                srti[w * 33 + l32] = (unsigned short)mi;
            }
        }
        __syncthreads();

        // (i1) waves 0..3: two-level merge (16 rows -> 4), write row 4w
        if (w < 4) {
            const int half = lane >> 5, l32 = lane & 31;
            const int rA = 4 * w + 2 * half, rB = rA + 1;
            float av = srtv[rA * 33 + l32];        int ai = srti[rA * 33 + l32];
            float bv = srtv[rB * 33 + (31 - l32)]; int bi = srti[rB * 33 + (31 - l32)];
            float mv; int mi;
            CMP_MAX(av, ai, bv, bi, mv, mi);
            CLEAN32(mv, mi, l32);
            float pv = __shfl_xor(mv, 63, 64);
            int   pi = __shfl_xor(mi, 63, 64);
            float m2; int i2;
            CMP_MAX(mv, mi, pv, pi, m2, i2);
            CLEAN32(m2, i2, l32);
            if (half == 0) {
                srtv[(4 * w) * 33 + l32] = m2;
                srti[(4 * w) * 33 + l32] = (unsigned short)i2;
            }
        }
        __syncthreads();

        // (i2) wave 0: two-level merge (4 rows -> 1) -> scores/btag/par
        if (w == 0) {
            const int half = lane >> 5, l32 = lane & 31;
            const int rA = 8 * half, rB = 8 * half + 4;
            float av = srtv[rA * 33 + l32];        int ai = srti[rA * 33 + l32];
            float bv = srtv[rB * 33 + (31 - l32)]; int bi = srti[rB * 33 + (31 - l32)];
            float mv; int mi;
            CMP_MAX(av, ai, bv, bi, mv, mi);
            CLEAN32(mv, mi, l32);
            float pv = __shfl_xor(mv, 63, 64);
            int   pi = __shfl_xor(mi, 63, 64);
            float fv; int fi;
            CMP_MAX(mv, mi, pv, pi, fv, fi);
            CLEAN32(fv, fi, l32);
            if (half == 0) {
                scores[l32] = fv;
                btag[l32] = fi & 31;
                par[l32] = fi >> 5;
            }
        }
        __syncthreads();
    }

    // ---- epilogue ----
    if (tid < 32) {
        float mx = scores[0];
        float ex = __expf(scores[tid] - mx);
        #pragma unroll
        for (int off = 16; off >= 1; off >>= 1) ex += __shfl_xor(ex, off, 32);
        if (tid == 0) {
            float logz = mx + logf(ex);
            atomicAdd(out, s_ps - logz);
        }
    }
}

extern "C" void kernel_launch(void* const* d_in, const int* in_sizes, int n_in,
                              void* d_out, int out_size, void* d_ws, size_t ws_size,
                              hipStream_t stream) {
    const float* emissions = (const float*)d_in[0];
    const int*   tags      = (const int*)d_in[1];
    const float* mask      = (const float*)d_in[2];
    const float* embedding = (const float*)d_in[3];
    const float* W_ih      = (const float*)d_in[4];
    const float* W_hh      = (const float*)d_in[5];
    const float* b_ih      = (const float*)d_in[6];
    const float* b_hh      = (const float*)d_in[7];
    const float* W_lin     = (const float*)d_in[8];
    const float* b_lin     = (const float*)d_in[9];
    float* out = (float*)d_out;

    char* ws = (char*)d_ws;
    float*  G    = (float*)ws;              // 33*768*4   = 101376 B
    float*  h1   = (float*)(ws + 101376);   // 256*4
    float*  tr0  = (float*)(ws + 102400);   // 32*4
    int2*   Wpk8 = (int2*)(ws + 102528);    // 24576*8    = 196608 B (fp8 frag-packed W_hh)
    __bf16* Wlpk = (__bf16*)(ws + 299136);  // 1024*8*2   = 16384 B  (bf16 frag-packed W_lin)

    hipMemsetAsync(d_out, 0, sizeof(float) * out_size, stream);
    k_pre<<<133, 256, 0, stream>>>(embedding, W_ih, b_ih, W_hh, W_lin, G, Wpk8, Wlpk);
    k_init<<<1, 256, 0, stream>>>(G, b_hh, W_lin, b_lin, h1, tr0);
    k_main<<<BAT, 1024, 0, stream>>>(emissions, tags, mask, G, h1, tr0,
                                     (const long*)Wpk8, Wlpk, b_hh, b_lin, out);
}

// Round 11
// 708.583 us; speedup vs baseline: 1.0298x; 1.0298x over previous
//
#include <hip/hip_runtime.h>

#define SEQ 64
#define BAT 256
#define NT 32
#define EMB 256
#define HID 256
#define G3 768   // 3*HID

typedef __bf16 bf16x8 __attribute__((ext_vector_type(8)));
typedef float f32x4 __attribute__((ext_vector_type(4)));

__device__ __forceinline__ float sigm_fast(float x) {
    return __builtin_amdgcn_rcpf(1.f + __expf(-x));   // inf-safe
}
__device__ __forceinline__ float tanh_fast(float x) {
    return 1.f - 2.f * __builtin_amdgcn_rcpf(__expf(2.f * x) + 1.f);
}
__device__ __forceinline__ float sigm(float x) {
    x = fminf(fmaxf(x, -30.f), 30.f);
    return 1.f / (1.f + __expf(-x));
}
__device__ __forceinline__ float tanhr(float x) {
    x = fminf(fmaxf(x, -15.f), 15.f);
    float e = __expf(2.f * x);
    return (e - 1.f) / (e + 1.f);
}

// ---- K1 (merged): G = emb @ W_ih.T + b_ih ; W_hh -> fp8 frag-pack ; W_lin -> bf16 pack;
//      block 32 additionally computes h1 = gru(emb[32], 0) and tr0 = h1 @ W_lin.T + b_lin.
__global__ void k_pre(const float* __restrict__ emb, const float* __restrict__ W_ih,
                      const float* __restrict__ b_ih, const float* __restrict__ W_hh,
                      const float* __restrict__ W_lin, const float* __restrict__ b_hh,
                      const float* __restrict__ b_lin,
                      float* __restrict__ G, int2* __restrict__ Wpk8, __bf16* __restrict__ Wlpk,
                      float* __restrict__ h1, float* __restrict__ tr0)
{
    const int tid = threadIdx.x;
    const int blk = blockIdx.x;
    if (blk < 33) {
        __shared__ float es[EMB];
        __shared__ float hs[HID];
        es[tid] = emb[blk * EMB + tid];
        __syncthreads();
        const float4* e4 = (const float4*)es;
        float gv[3];
        #pragma unroll
        for (int g = 0; g < 3; ++g) {
            int c = g * HID + tid;
            const float4* w4 = (const float4*)(W_ih + c * EMB);
            float acc = b_ih[c];
            #pragma unroll 8
            for (int i = 0; i < EMB / 4; ++i) {
                float4 a = e4[i], w = w4[i];
                acc += a.x * w.x + a.y * w.y + a.z * w.z + a.w * w.w;
            }
            G[blk * G3 + c] = acc;
            gv[g] = acc;
        }
        if (blk == 32) {            // h1 (exact fp32): thread tid owns column tid
            float r = sigm(gv[0] + b_hh[tid]);
            float z = sigm(gv[1] + b_hh[HID + tid]);
            float n = tanhr(gv[2] + r * b_hh[2 * HID + tid]);
            float h = (1.f - z) * n;     // h0 = 0
            h1[tid] = h; hs[tid] = h;
            __syncthreads();
            if (tid < NT) {
                const float4* w4 = (const float4*)(W_lin + tid * HID);
                const float4* h4 = (const float4*)hs;
                float acc = b_lin[tid];
                #pragma unroll 8
                for (int i = 0; i < HID / 4; ++i) {
                    float4 a = h4[i], w = w4[i];
                    acc += a.x * w.x + a.y * w.y + a.z * w.z + a.w * w.w;
                }
                tr0[tid] = acc;
            }
        }
    } else if (blk < 129) {                 // W_hh fp8 pack: 24576 chunks
        int idx  = (blk - 33) * 256 + tid;
        int c    = idx >> 9;
        int rem  = idx & 511;
        int kt   = rem >> 6;
        int lane = rem & 63;
        int row  = c * 16 + (lane & 15);
        int col  = kt * 32 + (lane >> 4) * 8;
        const float* src = W_hh + row * 256 + col;
        int lo = __builtin_amdgcn_cvt_pk_fp8_f32(src[0], src[1], 0, 0);
        lo     = __builtin_amdgcn_cvt_pk_fp8_f32(src[2], src[3], lo, 1);
        int hi = __builtin_amdgcn_cvt_pk_fp8_f32(src[4], src[5], 0, 0);
        hi     = __builtin_amdgcn_cvt_pk_fp8_f32(src[6], src[7], hi, 1);
        Wpk8[idx] = make_int2(lo, hi);
    } else {                                // W_lin bf16 pack: 1024 chunks
        int i2   = (blk - 129) * 256 + tid;
        int nt   = i2 >> 9;
        int rem  = i2 & 511;
        int kt   = rem >> 6;
        int lane = rem & 63;
        int row  = nt * 16 + (lane & 15);
        int col  = kt * 32 + (lane >> 4) * 8;
        const float* src = W_lin + row * 256 + col;
        bf16x8 v;
        #pragma unroll
        for (int j = 0; j < 8; ++j) v[j] = (__bf16)src[j];
        *(bf16x8*)(Wlpk + i2 * 8) = v;
    }
}

// merge-step helper: comparator (v desc, idx asc); 5-stage bitonic clean within 32-lane half
#define CMP_MAX(av, ai, bv, bi, mv, mi)                          \
    if ((av) > (bv) || ((av) == (bv) && (ai) < (bi))) { mv = (av); mi = (ai); } \
    else                                               { mv = (bv); mi = (bi); }
#define CLEAN32(mv, mi, l32)                                      \
    _Pragma("unroll")                                             \
    for (int off = 16; off >= 1; off >>= 1) {                     \
        float ov = __shfl_xor(mv, off, 64);                       \
        int   oi = __shfl_xor(mi, off, 64);                       \
        bool up = ((l32) & off) == 0;                             \
        bool omax = (ov > mv) || (ov == mv && oi < mi);           \
        if (up == omax) { mv = ov; mi = oi; }                     \
    }

// ---- K3: one 1024-thread workgroup per batch element; fp8 W_hh register-stationary;
//          6 barriers/step (ds_permute rank-sort + fused two-level merges).
__global__ __launch_bounds__(1024, 1) void k_main(
    const float* __restrict__ em, const int* __restrict__ tags, const float* __restrict__ mask,
    const float* __restrict__ G, const float* __restrict__ h1w, const float* __restrict__ tr0w,
    const long* __restrict__ Wpk8, const __bf16* __restrict__ Wlpk,
    const float* __restrict__ bhhg, const float* __restrict__ bling,
    float* __restrict__ out)
{
    __shared__ __attribute__((aligned(16))) __bf16 gl[33 * 784];        // bf16 G (33 embeddings)
    __shared__ __attribute__((aligned(16))) __bf16 hb[2][48 * 264];     // bf16 state ping-pong (rows 33..47 zero)
    __shared__ __attribute__((aligned(16))) unsigned char hq[48 * 272]; // fp8 permuted A (rows 33..47 zero)
    __shared__ __attribute__((aligned(16))) __bf16 wlin[8192];          // packed W_lin frags
    __shared__ float trs[33 * 33];
    __shared__ float srtv[16 * 33];
    __shared__ unsigned short srti[16 * 33];
    __shared__ float em_s[SEQ * NT];
    __shared__ float mask_s[SEQ];
    __shared__ int tags_s[SEQ];
    __shared__ float scores[NT];
    __shared__ int btag[NT], par[NT];
    __shared__ float s_ps;

    const int tid = threadIdx.x;
    const int b = blockIdx.x;
    const int w = tid >> 6;
    const int lane = tid & 63;
    const int q = lane >> 4;
    const int l15 = lane & 15;
    const int j = w * 16 + l15;          // this lane's hidden column

    // ---- register-stationary W_hh fragments & biases ----
    long wreg[24];
    #pragma unroll
    for (int g = 0; g < 3; ++g)
        #pragma unroll
        for (int kt = 0; kt < 8; ++kt)
            wreg[g * 8 + kt] = Wpk8[((g * 16 + w) * 8 + kt) * 64 + lane];
    const float br_ = bhhg[j], bz_ = bhhg[256 + j], bn_ = bhhg[512 + j];
    float bl_ = 0.f;
    if (w < 6) bl_ = bling[(w & 1) * 16 + l15];

    // ---- prologue staging ----
    if (tid < 64) mask_s[tid] = mask[tid * BAT + b];
    else if (tid < 128) tags_s[tid - 64] = tags[(tid - 64) * BAT + b];
    else if (tid < 160) par[tid - 128] = tid - 128;
    ((bf16x8*)wlin)[tid] = ((const bf16x8*)Wlpk)[tid];
    for (int idx = tid; idx < SEQ * NT; idx += 1024)
        em_s[idx] = em[((idx >> 5) * BAT + b) * NT + (idx & 31)];
    for (int idx = tid; idx < 33 * 768; idx += 1024) {
        int row = idx / 768, col = idx - row * 768;
        gl[row * 784 + col] = (__bf16)G[idx];
    }
    for (int idx = tid; idx < 33 * 256; idx += 1024)
        hb[0][(idx >> 8) * 264 + (idx & 255)] = (__bf16)h1w[idx & 255];
    for (int idx = tid; idx < 15 * 264; idx += 1024) {      // zero pad rows 33..47
        hb[0][33 * 264 + idx] = (__bf16)0.f;
        hb[1][33 * 264 + idx] = (__bf16)0.f;
    }
    for (int idx = tid; idx < 15 * 272 / 8; idx += 1024)
        *(long*)&hq[33 * 272 + idx * 8] = 0L;
    __syncthreads();

    // ---- initial top_k of s_init = (trans0 + em0) * mask0 (rank sort, ties -> lower idx) ----
    if (tid < 32) {
        float m0 = mask_s[0];
        float v = (tr0w[tid] + em_s[tid]) * m0;
        int cnt = 0;
        for (int jj = 0; jj < 32; ++jj) {
            float vj = __shfl(v, jj, 32);
            cnt += (vj > v) || (vj == v && jj < tid);
        }
        scores[cnt] = v; btag[cnt] = tid;
    }
    if (tid == 64) {
        int t0 = tags_s[0];
        s_ps = (tr0w[t0] + em_s[t0]) * mask_s[0];
    }
    __syncthreads();

    for (int t = 1; t < SEQ; ++t) {
        const int cur = (t - 1) & 1, nxt = t & 1;

        // (b) hq <- fp8(parent-permuted h) ; permutation applied at WRITE
        for (int c = tid; c < 33 * 32; c += 1024) {
            int row = c >> 5, off = (c & 31) * 8;
            int src = (row < 32) ? par[row] : 32;
            bf16x8 hv = *(const bf16x8*)&hb[cur][src * 264 + off];
            int lo = __builtin_amdgcn_cvt_pk_fp8_f32((float)hv[0], (float)hv[1], 0, 0);
            lo     = __builtin_amdgcn_cvt_pk_fp8_f32((float)hv[2], (float)hv[3], lo, 1);
            int hi = __builtin_amdgcn_cvt_pk_fp8_f32((float)hv[4], (float)hv[5], 0, 0);
            hi     = __builtin_amdgcn_cvt_pk_fp8_f32((float)hv[6], (float)hv[7], hi, 1);
            *(int2*)&hq[row * 272 + off] = make_int2(lo, hi);
        }
        __syncthreads();

        // (c) gh = hidden @ W_hh.T (fp8, fixed-row A reads; W from registers)
        f32x4 acc[3][3];
        #pragma unroll
        for (int mt = 0; mt < 3; ++mt)
            #pragma unroll
            for (int g = 0; g < 3; ++g) {
                f32x4 z = {0.f, 0.f, 0.f, 0.f};
                acc[mt][g] = z;
            }
        #pragma unroll
        for (int kt = 0; kt < 8; ++kt) {
            const int kb = kt * 32 + q * 8;
            long af0 = *(const long*)&hq[l15 * 272 + kb];
            long af1 = *(const long*)&hq[(16 + l15) * 272 + kb];
            long af2 = *(const long*)&hq[(32 + l15) * 272 + kb];
            #pragma unroll
            for (int g = 0; g < 3; ++g) {
                acc[0][g] = __builtin_amdgcn_mfma_f32_16x16x32_fp8_fp8(af0, wreg[g * 8 + kt], acc[0][g], 0, 0, 0);
                acc[1][g] = __builtin_amdgcn_mfma_f32_16x16x32_fp8_fp8(af1, wreg[g * 8 + kt], acc[1][g], 0, 0, 0);
                acc[2][g] = __builtin_amdgcn_mfma_f32_16x16x32_fp8_fp8(af2, wreg[g * 8 + kt], acc[2][g], 0, 0, 0);
            }
        }

        // (d1) GRU elementwise; hold from bf16 hb[cur][par]; writes bf16 hb[nxt] only
        {
            const int pt = tags_s[t - 1];
            #pragma unroll
            for (int mt = 0; mt < 2; ++mt) {
                #pragma unroll
                for (int r = 0; r < 4; ++r) {
                    const int row = mt * 16 + q * 4 + r;          // 0..31
                    const int e = btag[row], src = par[row];
                    const __bf16* gp = &gl[e * 784 + j];
                    float rr = sigm_fast((float)gp[0]   + acc[mt][0][r] + br_);
                    float zz = sigm_fast((float)gp[256] + acc[mt][1][r] + bz_);
                    float nn = tanh_fast((float)gp[512] + rr * (acc[mt][2][r] + bn_));
                    float hold = (float)hb[cur][src * 264 + j];
                    hb[nxt][row * 264 + j] = (__bf16)(zz * (hold - nn) + nn);
                }
            }
            if (lane < 16) {                                      // path row 32 (mt=2,q=0,r=0)
                const __bf16* gp = &gl[pt * 784 + j];
                float rr = sigm_fast((float)gp[0]   + acc[2][0][0] + br_);
                float zz = sigm_fast((float)gp[256] + acc[2][1][0] + bz_);
                float nn = tanh_fast((float)gp[512] + rr * (acc[2][2][0] + bn_));
                float hold = (float)hb[cur][32 * 264 + j];
                hb[nxt][32 * 264 + j] = (__bf16)(zz * (hold - nn) + nn);
            }
        }
        __syncthreads();

        // (e) tr = hnew @ W_lin.T + b_lin (bf16; waves 0..5: mt = w>>1, coltile = w&1)
        if (w < 6) {
            const int mt = w >> 1, ntc = w & 1;
            f32x4 a2 = {0.f, 0.f, 0.f, 0.f};
            #pragma unroll
            for (int kt = 0; kt < 8; ++kt) {
                const int kk = kt * 32 + q * 8;
                bf16x8 af = *(const bf16x8*)&hb[nxt][(mt * 16 + l15) * 264 + kk];
                bf16x8 bv = *(const bf16x8*)&wlin[((ntc * 8 + kt) * 64 + lane) * 8];
                a2 = __builtin_amdgcn_mfma_f32_16x16x32_bf16(af, bv, a2, 0, 0, 0);
            }
            #pragma unroll
            for (int r = 0; r < 4; ++r) {
                int row = mt * 16 + q * 4 + r;
                if (row <= 32) trs[row * 33 + ntc * 16 + l15] = a2[r] + bl_;
            }
        }
        __syncthreads();

        // (f) path score + rank-sort via ds_permute + intra-wave merge L1 -> srtv row w
        const float m_t = mask_s[t];
        if (tid == 0) {
            int ct = tags_s[t];
            s_ps += (trs[32 * 33 + ct] + em_s[ct]) * m_t;
        }
        {
            const int half = lane >> 5, l32 = lane & 31;
            const int k = w * 2 + half;                 // this half's candidate row
            float bse = scores[btag[k]];                // faithful quirk: gather by prev TAG id
            float v = bse + (trs[k * 33 + l32] + em_s[t * 32 + l32]) * m_t;
            int fidx = k * 32 + l32;
            int cnt = 0;
            #pragma unroll
            for (int jj = 0; jj < 32; ++jj) {
                float vj = __shfl(v, jj, 32);
                cnt += (vj > v) || (vj == v && jj < l32);
            }
            // in-register scatter: sorted position within this half's 32 lanes
            int tgt = (half * 32 + cnt) * 4;
            float sv = __int_as_float(__builtin_amdgcn_ds_permute(tgt, __float_as_int(v)));
            int   si = __builtin_amdgcn_ds_permute(tgt, fidx);
            // cross-half merge (rows 2w, 2w+1): partner at reversed index = lane^63
            float pv = __shfl_xor(sv, 63, 64);
            int   pi = __shfl_xor(si, 63, 64);
            float mv; int mi;
            CMP_MAX(sv, si, pv, pi, mv, mi);
            CLEAN32(mv, mi, l32);
            if (half == 0) {
                srtv[w * 33 + l32] = mv;
                srti[w * 33 + l32] = (unsigned short)mi;
            }
        }
        __syncthreads();

        // (i1) waves 0..3: two-level merge (16 rows -> 4), write row 4w
        if (w < 4) {
            const int half = lane >> 5, l32 = lane & 31;
            const int rA = 4 * w + 2 * half, rB = rA + 1;
            float av = srtv[rA * 33 + l32];        int ai = srti[rA * 33 + l32];
            float bv = srtv[rB * 33 + (31 - l32)]; int bi = srti[rB * 33 + (31 - l32)];
            float mv; int mi;
            CMP_MAX(av, ai, bv, bi, mv, mi);
            CLEAN32(mv, mi, l32);
            float pv = __shfl_xor(mv, 63, 64);
            int   pi = __shfl_xor(mi, 63, 64);
            float m2; int i2;
            CMP_MAX(mv, mi, pv, pi, m2, i2);
            CLEAN32(m2, i2, l32);
            if (half == 0) {
                srtv[(4 * w) * 33 + l32] = m2;
                srti[(4 * w) * 33 + l32] = (unsigned short)i2;
            }
        }
        __syncthreads();

        // (i2) wave 0: two-level merge (4 rows -> 1) -> scores/btag/par
        if (w == 0) {
            const int half = lane >> 5, l32 = lane & 31;
            const int rA = 8 * half, rB = 8 * half + 4;
            float av = srtv[rA * 33 + l32];        int ai = srti[rA * 33 + l32];
            float bv = srtv[rB * 33 + (31 - l32)]; int bi = srti[rB * 33 + (31 - l32)];
            float mv; int mi;
            CMP_MAX(av, ai, bv, bi, mv, mi);
            CLEAN32(mv, mi, l32);
            float pv = __shfl_xor(mv, 63, 64);
            int   pi = __shfl_xor(mi, 63, 64);
            float fv; int fi;
            CMP_MAX(mv, mi, pv, pi, fv, fi);
            CLEAN32(fv, fi, l32);
            if (half == 0) {
                scores[l32] = fv;
                btag[l32] = fi & 31;
                par[l32] = fi >> 5;
            }
        }
        __syncthreads();
    }

    // ---- epilogue ----
    if (tid < 32) {
        float mx = scores[0];
        float ex = __expf(scores[tid] - mx);
        #pragma unroll
        for (int off = 16; off >= 1; off >>= 1) ex += __shfl_xor(ex, off, 32);
        if (tid == 0) {
            float logz = mx + logf(ex);
            atomicAdd(out, s_ps - logz);
        }
    }
}

extern "C" void kernel_launch(void* const* d_in, const int* in_sizes, int n_in,
                              void* d_out, int out_size, void* d_ws, size_t ws_size,
                              hipStream_t stream) {
    const float* emissions = (const float*)d_in[0];
    const int*   tags      = (const int*)d_in[1];
    const float* mask      = (const float*)d_in[2];
    const float* embedding = (const float*)d_in[3];
    const float* W_ih      = (const float*)d_in[4];
    const float* W_hh      = (const float*)d_in[5];
    const float* b_ih      = (const float*)d_in[6];
    const float* b_hh      = (const float*)d_in[7];
    const float* W_lin     = (const float*)d_in[8];
    const float* b_lin     = (const float*)d_in[9];
    float* out = (float*)d_out;

    char* ws = (char*)d_ws;
    float*  G    = (float*)ws;              // 33*768*4   = 101376 B
    float*  h1   = (float*)(ws + 101376);   // 256*4
    float*  tr0  = (float*)(ws + 102400);   // 32*4
    int2*   Wpk8 = (int2*)(ws + 102528);    // 24576*8    = 196608 B (fp8 frag-packed W_hh)
    __bf16* Wlpk = (__bf16*)(ws + 299136);  // 1024*8*2   = 16384 B  (bf16 frag-packed W_lin)

    hipMemsetAsync(d_out, 0, sizeof(float) * out_size, stream);
    k_pre<<<133, 256, 0, stream>>>(embedding, W_ih, b_ih, W_hh, W_lin, b_hh, b_lin,
                                   G, Wpk8, Wlpk, h1, tr0);
    k_main<<<BAT, 1024, 0, stream>>>(emissions, tags, mask, G, h1, tr0,
                                     (const long*)Wpk8, Wlpk, b_hh, b_lin, out);
}